// Round 1
// baseline (1147.402 us; speedup 1.0000x reference)
//
#include <hip/hip_runtime.h>

// AdultConnectomeNetwork: 3 layers of xt = A_sp @ (W_sp @ xt) + bias
// State layout: xt[N][B], B=32 contiguous floats (one 128B line per neuron).
// Each edge handled by 32 lanes (half-wave): coalesced gather + coalesced
// atomic scatter.

#define NN 50000
#define NNZ_E 1600000
#define BATCH 32
#define NB (NN * BATCH)

__global__ void transpose_in_kernel(const float* __restrict__ x,
                                    float* __restrict__ xt) {
    int i = blockIdx.x * blockDim.x + threadIdx.x;  // i = n*B + b
    if (i < NB) {
        int n = i >> 5;
        int b = i & 31;
        xt[i] = x[b * NN + n];
    }
}

__global__ void fill_zero_kernel(float* __restrict__ p) {
    int i = blockIdx.x * blockDim.x + threadIdx.x;
    if (i < NB) p[i] = 0.0f;
}

__global__ void fill_bias_kernel(const float* __restrict__ bias,
                                 float* __restrict__ p) {
    int i = blockIdx.x * blockDim.x + threadIdx.x;
    if (i < NB) p[i] = bias[i >> 5];
}

__global__ void spmm_atomic_kernel(const float* __restrict__ vals,
                                   const int* __restrict__ row,
                                   const int* __restrict__ col,
                                   const float* __restrict__ in,
                                   float* __restrict__ out) {
    int t = blockIdx.x * blockDim.x + threadIdx.x;
    int e = t >> 5;       // edge index: 32 lanes per edge
    int b = t & 31;       // batch lane
    if (e < NNZ_E) {
        float v = vals[e];
        int c = col[e];
        int r = row[e];
        atomicAdd(&out[(r << 5) + b], v * in[(c << 5) + b]);
    }
}

__global__ void transpose_out_kernel(const float* __restrict__ xt,
                                     float* __restrict__ out) {
    int i = blockIdx.x * blockDim.x + threadIdx.x;  // i = b*N + n (coalesced write)
    if (i < NB) {
        int b = i / NN;
        int n = i - b * NN;
        out[i] = xt[(n << 5) + b];
    }
}

extern "C" void kernel_launch(void* const* d_in, const int* in_sizes, int n_in,
                              void* d_out, int out_size, void* d_ws, size_t ws_size,
                              hipStream_t stream) {
    const float* x        = (const float*)d_in[0];
    const float* adj_vals = (const float*)d_in[1];
    const float* w_vals   = (const float*)d_in[2];
    const float* bias     = (const float*)d_in[3];
    const int*   row      = (const int*)d_in[4];
    const int*   col      = (const int*)d_in[5];
    float* out = (float*)d_out;

    float* xt  = (float*)d_ws;          // [N][B]
    float* tmp = xt + NB;               // [N][B]

    const int BS = 256;
    const int grid_nb   = (NB + BS - 1) / BS;
    const int grid_edge = (NNZ_E * 32 + BS - 1) / BS;

    transpose_in_kernel<<<grid_nb, BS, 0, stream>>>(x, xt);

    for (int layer = 0; layer < 3; ++layer) {
        // tmp = W @ xt
        fill_zero_kernel<<<grid_nb, BS, 0, stream>>>(tmp);
        spmm_atomic_kernel<<<grid_edge, BS, 0, stream>>>(w_vals, row, col, xt, tmp);
        // xt = A @ tmp + bias
        fill_bias_kernel<<<grid_nb, BS, 0, stream>>>(bias, xt);
        spmm_atomic_kernel<<<grid_edge, BS, 0, stream>>>(adj_vals, row, col, tmp, xt);
    }

    transpose_out_kernel<<<grid_nb, BS, 0, stream>>>(xt, out);
}

// Round 2
// 484.835 us; speedup vs baseline: 2.3666x; 2.3666x over previous
//
#include <hip/hip_runtime.h>

// AdultConnectomeNetwork: 3 layers of xt = A_sp @ (W_sp @ xt) + bias.
// Round 2: COO -> CSR counting sort in-launch (one sort serves all 6 SpMM
// passes), then atomic-free gather-SpMM: one 32-lane half-wave per row,
// register accumulate, single coalesced 128B store per row.
// State layout: xt[N][32] (one 128B line per neuron).

#define NN 50000
#define NNZ_E 1600000
#define NB (NN * 32)
#define SCAN_BS 256
#define NBLK ((NN + SCAN_BS - 1) / SCAN_BS)   // 196

__global__ void zero_counts_kernel(int* __restrict__ counts) {
    int i = blockIdx.x * blockDim.x + threadIdx.x;
    if (i < NN) counts[i] = 0;
}

__global__ void hist_kernel(const int* __restrict__ row, int* __restrict__ counts) {
    int e = blockIdx.x * blockDim.x + threadIdx.x;
    if (e < NNZ_E) atomicAdd(&counts[row[e]], 1);
}

// In-place: counts[i] -> exclusive-scan-within-block; bsum[blk] = block total.
__global__ void scan_block_kernel(int* __restrict__ data, int* __restrict__ bsum) {
    __shared__ int s[SCAN_BS];
    int i = blockIdx.x * SCAN_BS + threadIdx.x;
    int v = (i < NN) ? data[i] : 0;
    s[threadIdx.x] = v;
    __syncthreads();
    for (int off = 1; off < SCAN_BS; off <<= 1) {
        int t = (threadIdx.x >= off) ? s[threadIdx.x - off] : 0;
        __syncthreads();
        s[threadIdx.x] += t;
        __syncthreads();
    }
    if (i < NN) data[i] = s[threadIdx.x] - v;              // exclusive within block
    if (threadIdx.x == SCAN_BS - 1) bsum[blockIdx.x] = s[threadIdx.x];
}

__global__ void scan_bsum_kernel(int* __restrict__ bsum) {
    if (blockIdx.x == 0 && threadIdx.x == 0) {
        int acc = 0;
        for (int i = 0; i < NBLK; ++i) { int v = bsum[i]; bsum[i] = acc; acc += v; }
    }
}

__global__ void scan_finalize_kernel(const int* __restrict__ excl,
                                     const int* __restrict__ boff,
                                     int* __restrict__ row_start,
                                     int* __restrict__ cursor) {
    int i = blockIdx.x * blockDim.x + threadIdx.x;
    if (i < NN) {
        int v = excl[i] + boff[i / SCAN_BS];
        row_start[i] = v;
        cursor[i] = v;
    }
    if (i == 0) row_start[NN] = NNZ_E;
}

__global__ void scatter_kernel(const int* __restrict__ row, const int* __restrict__ col,
                               const float* __restrict__ a, const float* __restrict__ w,
                               int* __restrict__ cursor,
                               int* __restrict__ col_s, float* __restrict__ a_s,
                               float* __restrict__ w_s) {
    int e = blockIdx.x * blockDim.x + threadIdx.x;
    if (e < NNZ_E) {
        int r = row[e];
        int pos = atomicAdd(&cursor[r], 1);
        col_s[pos] = col[e];
        a_s[pos]   = a[e];
        w_s[pos]   = w[e];
    }
}

__global__ void transpose_in_kernel(const float* __restrict__ x,
                                    float* __restrict__ xt) {
    int i = blockIdx.x * blockDim.x + threadIdx.x;  // i = n*32 + b
    if (i < NB) {
        int n = i >> 5;
        int b = i & 31;
        xt[i] = x[b * NN + n];
    }
}

// One 32-lane half-wave per row; lane = batch column. Atomic-free.
__global__ __launch_bounds__(256) void spmm_csr_kernel(
        const float* __restrict__ vals, const int* __restrict__ col_s,
        const int* __restrict__ row_start, const float* __restrict__ in,
        float* __restrict__ out, const float* __restrict__ bias) {
    int t = blockIdx.x * blockDim.x + threadIdx.x;
    int r = t >> 5;
    int b = t & 31;
    if (r >= NN) return;
    int s = row_start[r];
    int e = row_start[r + 1];
    float acc = bias ? bias[r] : 0.0f;
    int i = s;
    for (; i + 4 <= e; i += 4) {        // 4 gathers in flight per half-wave
        int   c0 = col_s[i],     c1 = col_s[i + 1];
        int   c2 = col_s[i + 2], c3 = col_s[i + 3];
        float v0 = vals[i],      v1 = vals[i + 1];
        float v2 = vals[i + 2],  v3 = vals[i + 3];
        acc += v0 * in[(c0 << 5) + b];
        acc += v1 * in[(c1 << 5) + b];
        acc += v2 * in[(c2 << 5) + b];
        acc += v3 * in[(c3 << 5) + b];
    }
    for (; i < e; ++i)
        acc += vals[i] * in[(col_s[i] << 5) + b];
    out[(r << 5) + b] = acc;
}

__global__ void transpose_out_kernel(const float* __restrict__ xt,
                                     float* __restrict__ out) {
    int i = blockIdx.x * blockDim.x + threadIdx.x;  // i = b*N + n (coalesced write)
    if (i < NB) {
        int b = i / NN;
        int n = i - b * NN;
        out[i] = xt[(n << 5) + b];
    }
}

extern "C" void kernel_launch(void* const* d_in, const int* in_sizes, int n_in,
                              void* d_out, int out_size, void* d_ws, size_t ws_size,
                              hipStream_t stream) {
    const float* x        = (const float*)d_in[0];
    const float* adj_vals = (const float*)d_in[1];
    const float* w_vals   = (const float*)d_in[2];
    const float* bias     = (const float*)d_in[3];
    const int*   row      = (const int*)d_in[4];
    const int*   col      = (const int*)d_in[5];
    float* out = (float*)d_out;

    // Workspace layout (all 4-byte elements), total ~32.6 MB
    float* xt        = (float*)d_ws;            // NB
    float* tmp       = xt + NB;                 // NB
    float* a_s       = tmp + NB;                // NNZ_E
    float* w_s       = a_s + NNZ_E;             // NNZ_E
    int*   col_s     = (int*)(w_s + NNZ_E);     // NNZ_E
    int*   counts    = col_s + NNZ_E;           // NN (becomes excl block-scan)
    int*   row_start = counts + NN;             // NN+1
    int*   cursor    = row_start + NN + 1;      // NN
    int*   bsum      = cursor + NN;             // NBLK

    const int BS = 256;
    const int grid_n    = (NN + BS - 1) / BS;       // 196
    const int grid_nb   = (NB + BS - 1) / BS;       // 6250
    const int grid_edge = (NNZ_E + BS - 1) / BS;    // 6250

    // ---- COO -> CSR counting sort (once; serves all 6 passes) ----
    zero_counts_kernel<<<grid_n, BS, 0, stream>>>(counts);
    hist_kernel<<<grid_edge, BS, 0, stream>>>(row, counts);
    scan_block_kernel<<<NBLK, SCAN_BS, 0, stream>>>(counts, bsum);
    scan_bsum_kernel<<<1, 64, 0, stream>>>(bsum);
    scan_finalize_kernel<<<grid_n, BS, 0, stream>>>(counts, bsum, row_start, cursor);
    scatter_kernel<<<grid_edge, BS, 0, stream>>>(row, col, adj_vals, w_vals,
                                                 cursor, col_s, a_s, w_s);

    // ---- dense state in [N][32] layout ----
    transpose_in_kernel<<<grid_nb, BS, 0, stream>>>(x, xt);

    for (int layer = 0; layer < 3; ++layer) {
        spmm_csr_kernel<<<grid_nb, BS, 0, stream>>>(w_s, col_s, row_start, xt, tmp, nullptr);
        spmm_csr_kernel<<<grid_nb, BS, 0, stream>>>(a_s, col_s, row_start, tmp, xt, bias);
    }

    transpose_out_kernel<<<grid_nb, BS, 0, stream>>>(xt, out);
}